// Round 2
// baseline (541.471 us; speedup 1.0000x reference)
//
#include <hip/hip_runtime.h>
#include <math.h>

#define Hd 128
#define Wd 128
#define HW 16384

__device__ __forceinline__ float wred(float v) {
  #pragma unroll
  for (int o = 32; o > 0; o >>= 1) v += __shfl_down(v, o, 64);
  return v;
}

// ---- K1: grouped 3x3 key conv + ReLU.  grid (8,8,B*8), block 256 = 16x16 pixels ----
// z = b*8 + g  (each (b,g) block loads its own 8-channel tile: no redundant traffic)
__global__ __launch_bounds__(256) void k_keyconv(const float* __restrict__ x,
                                                 const float* __restrict__ wkey,
                                                 float* __restrict__ kout) {
  __shared__ float xt[8][18][18];
  const int tid = threadIdx.x;
  const int tx = tid & 15, ty = tid >> 4;
  const int b = blockIdx.z >> 3, g = blockIdx.z & 7;
  const int h0 = blockIdx.y * 16, w0 = blockIdx.x * 16;
  const int h = h0 + ty, w = w0 + tx;
  for (int i = tid; i < 8 * 324; i += 256) {
    int ch = i / 324, r = i - ch * 324;
    int yy = r / 18, xx = r - yy * 18;
    int gh = h0 + yy - 1, gw = w0 + xx - 1;
    float v = 0.f;
    if (gh >= 0 && gh < Hd && gw >= 0 && gw < Wd)
      v = x[((long)(b * 64 + g * 8 + ch) << 14) + (gh << 7) + gw];
    xt[ch][yy][xx] = v;
  }
  __syncthreads();
  float acc[8] = {0.f, 0.f, 0.f, 0.f, 0.f, 0.f, 0.f, 0.f};
  const float* wg = wkey + g * 576;  // w_key rows [8g, 8g+8), each 72 floats
  #pragma unroll
  for (int i = 0; i < 8; ++i) {
    float nb[9];
    #pragma unroll
    for (int dy = 0; dy < 3; ++dy)
      #pragma unroll
      for (int dx = 0; dx < 3; ++dx)
        nb[dy * 3 + dx] = xt[i][ty + dy][tx + dx];
    #pragma unroll
    for (int oc = 0; oc < 8; ++oc) {
      const float* wr = wg + oc * 72 + i * 9;  // uniform -> scalar loads
      #pragma unroll
      for (int t = 0; t < 9; ++t) acc[oc] += wr[t] * nb[t];
    }
  }
  #pragma unroll
  for (int oc = 0; oc < 8; ++oc)
    kout[((long)(b * 64 + g * 8 + oc) << 14) + (h << 7) + w] = fmaxf(acc[oc], 0.f);
}

// ---- K2: pointwise e1+e2 (dynamic kernels) + c1 (value path) + GN partial stats ----
// grid (64, B, 2), block 256. z = s. xv OVERWRITES the k buffer in place: the only
// reused addresses (channels 32s..32s+31 at pixel p) are read (kc) then written (xv)
// by the SAME thread; all other threads/blocks touch disjoint addresses.
__global__ __launch_bounds__(256) void k_embed(const float* __restrict__ x,
                                               float* __restrict__ kxv,
                                               const float* __restrict__ we1,
                                               const float* __restrict__ we2,
                                               const float* __restrict__ be2,
                                               const float* __restrict__ wc1,
                                               float* __restrict__ wpre,
                                               float* __restrict__ stat) {
  const int tid = threadIdx.x;
  const int p = blockIdx.x * 256 + tid;
  const int b = blockIdx.y;
  const int s = blockIdx.z;
  float xc[32], kc[32];
  #pragma unroll
  for (int j = 0; j < 32; ++j) {
    xc[j] = x[((long)(b * 64 + 32 * s + j) << 14) + p];
    kc[j] = kxv[((long)(b * 64 + 32 * s + j) << 14) + p];
  }
  // value path: grouped 1x1 conv (32->32 per half), store xv over k slots
  #pragma unroll 4
  for (int o = 0; o < 32; ++o) {
    const float* wr = wc1 + (32 * s + o) * 32;
    float a = 0.f;
    #pragma unroll
    for (int j = 0; j < 32; ++j) a += wr[j] * xc[j];
    kxv[((long)(b * 64 + 32 * s + o) << 14) + p] = a;
  }
  // e1: 64(interleaved x,k) -> 16, ReLU
  float w1a[16];
  #pragma unroll
  for (int o = 0; o < 16; ++o) {
    const float* wr = we1 + (16 * s + o) * 64;
    float a = 0.f;
    #pragma unroll
    for (int j = 0; j < 32; ++j) a += wr[2 * j] * xc[j] + wr[2 * j + 1] * kc[j];
    w1a[o] = fmaxf(a, 0.f);
  }
  // e2: 16 -> 36 (+bias), store w_pre, accumulate GN sum/sumsq per group of 9
  #pragma unroll
  for (int gl = 0; gl < 4; ++gl) {
    float lgs = 0.f, lgq = 0.f;
    #pragma unroll
    for (int kk = 0; kk < 9; ++kk) {
      const int oc2 = 36 * s + gl * 9 + kk;
      const float* wr = we2 + oc2 * 16;
      float a = be2[oc2];
      #pragma unroll
      for (int ic = 0; ic < 16; ++ic) a += wr[ic] * w1a[ic];
      wpre[((long)(b * 72 + oc2) << 14) + p] = a;
      lgs += a;
      lgq += a * a;
    }
    float r1 = wred(lgs), r2 = wred(lgq);
    if ((tid & 63) == 0) {
      atomicAdd(&stat[(b * 8 + 4 * s + gl) * 2 + 0], r1);
      atomicAdd(&stat[(b * 8 + 4 * s + gl) * 2 + 1], r2);
    }
  }
}

// ---- K3: finalize GN stats ----
__global__ void k_gnstat(const float* __restrict__ stat, float* __restrict__ minv) {
  int i = threadIdx.x;
  if (i < 64) {
    const float N = 9.f * (float)HW;
    float s = stat[2 * i], q = stat[2 * i + 1];
    float m = s / N;
    float var = q / N - m * m;
    minv[2 * i] = m;
    minv[2 * i + 1] = rsqrtf(var + 1e-5f);
  }
}

// ---- K4: per-pixel local 3x3 conv with normalized dynamic kernels + CA partial sums ----
// grid (8,8,64), block 256 = 16x16 pixels.  z = b2*4 + g
__global__ __launch_bounds__(256) void k_local(const float* __restrict__ kxv,
                                               const float* __restrict__ wpre,
                                               const float* __restrict__ minv,
                                               const float* __restrict__ gnw,
                                               const float* __restrict__ gnb,
                                               float* __restrict__ out,
                                               float* __restrict__ ca) {
  __shared__ float xt[8][18][18];
  const int tid = threadIdx.x;
  const int tx = tid & 15, ty = tid >> 4;
  const int z = blockIdx.z;
  const int b2 = z >> 2, g = z & 3;
  const int t = b2 & 1, b = b2 >> 1;
  const int h0 = blockIdx.y * 16, w0 = blockIdx.x * 16;
  const int p = ((h0 + ty) << 7) + (w0 + tx);
  for (int i = tid; i < 8 * 324; i += 256) {
    int ch = i / 324, r = i - ch * 324;
    int yy = r / 18, xx = r - yy * 18;
    int gh = h0 + yy - 1, gw = w0 + xx - 1;
    float v = 0.f;
    if (gh >= 0 && gh < Hd && gw >= 0 && gw < Wd)
      v = kxv[((long)(b2 * 32 + g * 8 + ch) << 14) + (gh << 7) + gw];
    xt[ch][yy][xx] = v;
  }
  __syncthreads();
  const int gg = 4 * t + g;
  const float m = minv[(b * 8 + gg) * 2];
  const float inv = minv[(b * 8 + gg) * 2 + 1];
  float wn[9];
  #pragma unroll
  for (int kk = 0; kk < 9; ++kk) {
    const int ch72 = 36 * t + 9 * g + kk;
    float wv = wpre[((long)(b * 72 + ch72) << 14) + p];
    wn[kk] = (wv - m) * inv * gnw[ch72] + gnb[ch72];
  }
  #pragma unroll
  for (int cc = 0; cc < 8; ++cc) {
    float o = 0.f;
    #pragma unroll
    for (int dy = 0; dy < 3; ++dy)
      #pragma unroll
      for (int dx = 0; dx < 3; ++dx)
        o += wn[dy * 3 + dx] * xt[cc][ty + dy][tx + dx];
    out[((long)(b * 64 + t * 32 + g * 8 + cc) << 14) + p] = o;
    float os = wred(o);
    if ((tid & 63) == 0) atomicAdd(&ca[b * 64 + t * 32 + g * 8 + cc], os);
  }
}

// ---- K5: SE MLP (64 -> 4 relu -> 64 sigmoid) ----
__global__ void k_ca(const float* __restrict__ ca, const float* __restrict__ du1,
                     const float* __restrict__ du2, float* __restrict__ ys) {
  __shared__ float sy[8][64];
  __shared__ float sy4[8][4];
  const int tid = threadIdx.x;  // 512
  const int b = tid >> 6, c = tid & 63;
  sy[b][c] = ca[tid] * (1.f / (float)HW);
  __syncthreads();
  if (tid < 32) {
    int bb = tid >> 2, j = tid & 3;
    float a = 0.f;
    for (int c2 = 0; c2 < 64; ++c2) a += sy[bb][c2] * du1[j * 64 + c2];
    sy4[bb][j] = fmaxf(a, 0.f);
  }
  __syncthreads();
  float z = 0.f;
  #pragma unroll
  for (int j = 0; j < 4; ++j) z += sy4[b][j] * du2[c * 4 + j];
  ys[tid] = 1.f / (1.f + expf(-z));
}

// ---- K6: scale output by channel-attention gate ----
__global__ __launch_bounds__(256) void k_scale(float* __restrict__ out,
                                               const float* __restrict__ ys) {
  const long i4 = (long)blockIdx.x * 256 + threadIdx.x;  // float4 index
  const long e = i4 * 4;
  const int bc = (int)(e >> 14);  // b*64+c
  const float s = ys[bc];
  float4* o = (float4*)out;
  float4 v = o[i4];
  v.x *= s; v.y *= s; v.z *= s; v.w *= s;
  o[i4] = v;
}

extern "C" void kernel_launch(void* const* d_in, const int* in_sizes, int n_in,
                              void* d_out, int out_size, void* d_ws, size_t ws_size,
                              hipStream_t stream) {
  const float* x    = (const float*)d_in[0];
  const float* wkey = (const float*)d_in[1];
  const float* we1  = (const float*)d_in[2];
  const float* we2  = (const float*)d_in[3];
  const float* be2  = (const float*)d_in[4];
  const float* gnw  = (const float*)d_in[5];
  const float* gnb  = (const float*)d_in[6];
  const float* wc1  = (const float*)d_in[7];
  const float* du1  = (const float*)d_in[8];
  const float* du2  = (const float*)d_in[9];
  float* out = (float*)d_out;
  float* ws = (float*)d_ws;

  float* kxv  = ws;                    // 8*64*HW = 8388608 floats (k, then xv in place)
  float* wpre = ws + 8388608;          // 8*72*HW = 9437184 floats
  float* stat = ws + 17825792;         // 128 floats (GN sum/sumsq)
  float* ca   = stat + 128;            // 512 floats (CA channel sums)
  float* minv = ca + 512;              // 128 floats (GN mean/inv)
  float* ys   = minv + 128;            // 512 floats (SE gate)

  hipMemsetAsync(stat, 0, (128 + 512) * sizeof(float), stream);
  k_keyconv<<<dim3(8, 8, 64), 256, 0, stream>>>(x, wkey, kxv);
  k_embed<<<dim3(64, 8, 2), 256, 0, stream>>>(x, kxv, we1, we2, be2, wc1, wpre, stat);
  k_gnstat<<<1, 64, 0, stream>>>(stat, minv);
  k_local<<<dim3(8, 8, 64), 256, 0, stream>>>(kxv, wpre, minv, gnw, gnb, out, ca);
  k_ca<<<1, 512, 0, stream>>>(ca, du1, du2, ys);
  k_scale<<<8192, 256, 0, stream>>>(out, ys);
}

// Round 3
// 247.087 us; speedup vs baseline: 2.1914x; 2.1914x over previous
//
#include <hip/hip_runtime.h>
#include <math.h>

#define Hd 128
#define Wd 128
#define HW 16384

__device__ __forceinline__ float wred(float v) {
  #pragma unroll
  for (int o = 32; o > 0; o >>= 1) v += __shfl_down(v, o, 64);
  return v;
}

// ---- K1: grouped 3x3 key conv + ReLU.  grid (8,8,B*8), block 256 = 16x16 pixels ----
// z = b*8 + g. LDS rows padded to 24 floats: every wave LDS read is exact 2-way (free).
__global__ __launch_bounds__(256) void k_keyconv(const float* __restrict__ x,
                                                 const float* __restrict__ wkey,
                                                 float* __restrict__ kout) {
  __shared__ float xt[8][18][24];
  const int tid = threadIdx.x;
  const int tx = tid & 15, ty = tid >> 4;
  const int b = blockIdx.z >> 3, g = blockIdx.z & 7;
  const int h0 = blockIdx.y * 16, w0 = blockIdx.x * 16;
  const int h = h0 + ty, w = w0 + tx;
  for (int i = tid; i < 8 * 324; i += 256) {
    int ch = i / 324, r = i - ch * 324;
    int yy = r / 18, xx = r - yy * 18;
    int gh = h0 + yy - 1, gw = w0 + xx - 1;
    float v = 0.f;
    if (gh >= 0 && gh < Hd && gw >= 0 && gw < Wd)
      v = x[((long)(b * 64 + g * 8 + ch) << 14) + (gh << 7) + gw];
    xt[ch][yy][xx] = v;
  }
  __syncthreads();
  float acc[8] = {0.f, 0.f, 0.f, 0.f, 0.f, 0.f, 0.f, 0.f};
  const float* wg = wkey + g * 576;  // w_key rows [8g, 8g+8), each 72 floats
  #pragma unroll
  for (int i = 0; i < 8; ++i) {
    float nb[9];
    #pragma unroll
    for (int dy = 0; dy < 3; ++dy)
      #pragma unroll
      for (int dx = 0; dx < 3; ++dx)
        nb[dy * 3 + dx] = xt[i][ty + dy][tx + dx];
    #pragma unroll
    for (int oc = 0; oc < 8; ++oc) {
      const float* wr = wg + oc * 72 + i * 9;  // uniform -> scalar loads
      #pragma unroll
      for (int t = 0; t < 9; ++t) acc[oc] += wr[t] * nb[t];
    }
  }
  #pragma unroll
  for (int oc = 0; oc < 8; ++oc)
    kout[((long)(b * 64 + g * 8 + oc) << 14) + (h << 7) + w] = fmaxf(acc[oc], 0.f);
}

// ---- K2: pointwise e1+e2 + c1 + GN partial stats (NO atomics: per-wave slot store) ----
// grid (64, B, 2), block 256. z = s. xv overwrites k in place (same-thread read->write).
// spart layout: [row=256][col=128], row = bx*4+wave, col = (b*8+4s+gl)*2 + {0,1}.
__global__ __launch_bounds__(256) void k_embed(const float* __restrict__ x,
                                               float* __restrict__ kxv,
                                               const float* __restrict__ we1,
                                               const float* __restrict__ we2,
                                               const float* __restrict__ be2,
                                               const float* __restrict__ wc1,
                                               float* __restrict__ wpre,
                                               float* __restrict__ spart) {
  const int tid = threadIdx.x;
  const int p = blockIdx.x * 256 + tid;
  const int b = blockIdx.y;
  const int s = blockIdx.z;
  float xc[32], kc[32];
  #pragma unroll
  for (int j = 0; j < 32; ++j) {
    xc[j] = x[((long)(b * 64 + 32 * s + j) << 14) + p];
    kc[j] = kxv[((long)(b * 64 + 32 * s + j) << 14) + p];
  }
  // value path: grouped 1x1 conv (32->32 per half), store xv over k slots
  #pragma unroll 4
  for (int o = 0; o < 32; ++o) {
    const float* wr = wc1 + (32 * s + o) * 32;
    float a = 0.f;
    #pragma unroll
    for (int j = 0; j < 32; ++j) a += wr[j] * xc[j];
    kxv[((long)(b * 64 + 32 * s + o) << 14) + p] = a;
  }
  // e1: 64(interleaved x,k) -> 16, ReLU
  float w1a[16];
  #pragma unroll
  for (int o = 0; o < 16; ++o) {
    const float* wr = we1 + (16 * s + o) * 64;
    float a = 0.f;
    #pragma unroll
    for (int j = 0; j < 32; ++j) a += wr[2 * j] * xc[j] + wr[2 * j + 1] * kc[j];
    w1a[o] = fmaxf(a, 0.f);
  }
  // e2: 16 -> 36 (+bias), store w_pre, per-wave GN sum/sumsq -> spart slot
  const int row = blockIdx.x * 4 + (tid >> 6);
  #pragma unroll
  for (int gl = 0; gl < 4; ++gl) {
    float lgs = 0.f, lgq = 0.f;
    #pragma unroll
    for (int kk = 0; kk < 9; ++kk) {
      const int oc2 = 36 * s + gl * 9 + kk;
      const float* wr = we2 + oc2 * 16;
      float a = be2[oc2];
      #pragma unroll
      for (int ic = 0; ic < 16; ++ic) a += wr[ic] * w1a[ic];
      wpre[((long)(b * 72 + oc2) << 14) + p] = a;
      lgs += a;
      lgq += a * a;
    }
    float r1 = wred(lgs), r2 = wred(lgq);
    if ((tid & 63) == 0) {
      spart[row * 128 + (b * 8 + 4 * s + gl) * 2 + 0] = r1;
      spart[row * 128 + (b * 8 + 4 * s + gl) * 2 + 1] = r2;
    }
  }
}

// ---- K3: reduce spart columns + finalize GN stats. 1 block x 128 threads ----
__global__ void k_gnstat(const float* __restrict__ spart, float* __restrict__ minv) {
  __shared__ float sred[128];
  const int t = threadIdx.x;  // 128
  float a = 0.f;
  #pragma unroll 8
  for (int r = 0; r < 256; ++r) a += spart[r * 128 + t];
  sred[t] = a;
  __syncthreads();
  if (t < 64) {
    const float N = 9.f * (float)HW;
    float s = sred[2 * t], q = sred[2 * t + 1];
    float m = s / N;
    float var = q / N - m * m;
    minv[2 * t] = m;
    minv[2 * t + 1] = rsqrtf(var + 1e-5f);
  }
}

// ---- K4: per-pixel local 3x3 conv + CA partials (NO atomics). grid (8,8,64) ----
// part layout: [row=256][ch=512], row = tile*4+wave, ch = b2*32+g*8+cc.
__global__ __launch_bounds__(256) void k_local(const float* __restrict__ kxv,
                                               const float* __restrict__ wpre,
                                               const float* __restrict__ minv,
                                               const float* __restrict__ gnw,
                                               const float* __restrict__ gnb,
                                               float* __restrict__ out,
                                               float* __restrict__ part) {
  __shared__ float xt[8][18][24];
  const int tid = threadIdx.x;
  const int tx = tid & 15, ty = tid >> 4;
  const int z = blockIdx.z;
  const int b2 = z >> 2, g = z & 3;
  const int t = b2 & 1, b = b2 >> 1;
  const int h0 = blockIdx.y * 16, w0 = blockIdx.x * 16;
  const int tileid = blockIdx.y * 8 + blockIdx.x;
  const int p = ((h0 + ty) << 7) + (w0 + tx);
  for (int i = tid; i < 8 * 324; i += 256) {
    int ch = i / 324, r = i - ch * 324;
    int yy = r / 18, xx = r - yy * 18;
    int gh = h0 + yy - 1, gw = w0 + xx - 1;
    float v = 0.f;
    if (gh >= 0 && gh < Hd && gw >= 0 && gw < Wd)
      v = kxv[((long)(b2 * 32 + g * 8 + ch) << 14) + (gh << 7) + gw];
    xt[ch][yy][xx] = v;
  }
  __syncthreads();
  const int gg = 4 * t + g;
  const float m = minv[(b * 8 + gg) * 2];
  const float inv = minv[(b * 8 + gg) * 2 + 1];
  float wn[9];
  #pragma unroll
  for (int kk = 0; kk < 9; ++kk) {
    const int ch72 = 36 * t + 9 * g + kk;
    float wv = wpre[((long)(b * 72 + ch72) << 14) + p];
    wn[kk] = (wv - m) * inv * gnw[ch72] + gnb[ch72];
  }
  const int prow = tileid * 4 + (tid >> 6);
  #pragma unroll
  for (int cc = 0; cc < 8; ++cc) {
    float o = 0.f;
    #pragma unroll
    for (int dy = 0; dy < 3; ++dy)
      #pragma unroll
      for (int dx = 0; dx < 3; ++dx)
        o += wn[dy * 3 + dx] * xt[cc][ty + dy][tx + dx];
    const int ch512 = b2 * 32 + g * 8 + cc;
    out[((long)ch512 << 14) + p] = o;
    float os = wred(o);
    if ((tid & 63) == 0) part[prow * 512 + ch512] = os;
  }
}

// ---- K5: reduce CA partials + SE MLP (64 -> 4 relu -> 64 sigmoid). 1 block x 512 ----
__global__ void k_ca(const float* __restrict__ part, const float* __restrict__ du1,
                     const float* __restrict__ du2, float* __restrict__ ys) {
  __shared__ float sy[8][64];
  __shared__ float sy4[8][4];
  const int tid = threadIdx.x;  // 512
  const int b = tid >> 6, c = tid & 63;
  float acc = 0.f;
  #pragma unroll 8
  for (int r = 0; r < 256; ++r) acc += part[r * 512 + tid];
  sy[b][c] = acc * (1.f / (float)HW);
  __syncthreads();
  if (tid < 32) {
    int bb = tid >> 2, j = tid & 3;
    float a = 0.f;
    for (int c2 = 0; c2 < 64; ++c2) a += sy[bb][c2] * du1[j * 64 + c2];
    sy4[bb][j] = fmaxf(a, 0.f);
  }
  __syncthreads();
  float z = 0.f;
  #pragma unroll
  for (int j = 0; j < 4; ++j) z += sy4[b][j] * du2[c * 4 + j];
  ys[tid] = 1.f / (1.f + expf(-z));
}

// ---- K6: scale output by channel-attention gate ----
__global__ __launch_bounds__(256) void k_scale(float* __restrict__ out,
                                               const float* __restrict__ ys) {
  const long i4 = (long)blockIdx.x * 256 + threadIdx.x;  // float4 index
  const long e = i4 * 4;
  const int bc = (int)(e >> 14);  // b*64+c
  const float s = ys[bc];
  float4* o = (float4*)out;
  float4 v = o[i4];
  v.x *= s; v.y *= s; v.z *= s; v.w *= s;
  o[i4] = v;
}

extern "C" void kernel_launch(void* const* d_in, const int* in_sizes, int n_in,
                              void* d_out, int out_size, void* d_ws, size_t ws_size,
                              hipStream_t stream) {
  const float* x    = (const float*)d_in[0];
  const float* wkey = (const float*)d_in[1];
  const float* we1  = (const float*)d_in[2];
  const float* we2  = (const float*)d_in[3];
  const float* be2  = (const float*)d_in[4];
  const float* gnw  = (const float*)d_in[5];
  const float* gnb  = (const float*)d_in[6];
  const float* wc1  = (const float*)d_in[7];
  const float* du1  = (const float*)d_in[8];
  const float* du2  = (const float*)d_in[9];
  float* out = (float*)d_out;
  float* ws = (float*)d_ws;

  float* kxv  = ws;                    // 8*64*HW floats (k, then xv in place)
  float* wpre = ws + 8388608;          // 8*72*HW floats
  float* part = ws + 17825792;         // 131072 floats; spart (32768) overlays it
  float* spart = part;                 //   (disjoint lifetimes: embed/gnstat vs local/ca)
  float* minv = part + 131072;         // 128 floats
  float* ys   = minv + 128;            // 512 floats

  k_keyconv<<<dim3(8, 8, 64), 256, 0, stream>>>(x, wkey, kxv);
  k_embed<<<dim3(64, 8, 2), 256, 0, stream>>>(x, kxv, we1, we2, be2, wc1, wpre, spart);
  k_gnstat<<<1, 128, 0, stream>>>(spart, minv);
  k_local<<<dim3(8, 8, 64), 256, 0, stream>>>(kxv, wpre, minv, gnw, gnb, out, part);
  k_ca<<<1, 512, 0, stream>>>(part, du1, du2, ys);
  k_scale<<<8192, 256, 0, stream>>>(out, ys);
}